// Round 13
// baseline (462.212 us; speedup 1.0000x reference)
//
#include <hip/hip_runtime.h>

#define LN_EPS 1e-5f

typedef float f32x4 __attribute__((ext_vector_type(4)));
typedef short bf16x8 __attribute__((ext_vector_type(8)));
typedef unsigned short u16x4 __attribute__((ext_vector_type(4)));

__device__ __forceinline__ unsigned short f2bf(float f) {
  unsigned int u = __float_as_uint(f);
  u = (u + 0x7fffu + ((u >> 16) & 1u)) >> 16;
  return (unsigned short)u;
}
__device__ __forceinline__ float bf2f(unsigned short h) {
  return __uint_as_float((unsigned int)h << 16);
}
__device__ __forceinline__ float sigm(float x) {
  return 1.f / (1.f + __expf(-x));
}

// ============ fused: weight cvt (blocks [0,384)) + hist+rank (rest) ============
__global__ __launch_bounds__(256) void cvt_hist(const float* __restrict__ wa,
                                                const float* __restrict__ wb,
                                                const float* __restrict__ wc,
                                                const float* __restrict__ wd,
                                                unsigned short* __restrict__ oa,
                                                unsigned short* __restrict__ ob,
                                                unsigned short* __restrict__ oc,
                                                unsigned short* __restrict__ od,
                                                const int* __restrict__ ci,
                                                const int* __restrict__ vi,
                                                int* __restrict__ cntC,
                                                int* __restrict__ cntV,
                                                int* __restrict__ rankC,
                                                int* __restrict__ rankV, int E, int hgrid) {
  if ((int)blockIdx.x < 384) {
    int i = blockIdx.x * 256 + threadIdx.x;
    if (i < 16384) oa[i] = f2bf(wa[i]);
    else if (i < 49152) ob[i - 16384] = f2bf(wb[i - 16384]);
    else if (i < 65536) oc[i - 49152] = f2bf(wc[i - 49152]);
    else if (i < 98304) od[i - 65536] = f2bf(wd[i - 65536]);
    return;
  }
  int hb = blockIdx.x - 384;
  int tid = hb * 256 + threadIdx.x;
  int T = hgrid * 256;
  int e[4], c[4], v[4];
  bool ok[4];
#pragma unroll
  for (int i = 0; i < 4; ++i) {
    e[i] = tid + i * T;
    ok[i] = e[i] < E;
  }
#pragma unroll
  for (int i = 0; i < 4; ++i) if (ok[i]) c[i] = ci[e[i]];
#pragma unroll
  for (int i = 0; i < 4; ++i) if (ok[i]) v[i] = vi[e[i]];
  int rc[4], rv[4];
#pragma unroll
  for (int i = 0; i < 4; ++i) if (ok[i]) rc[i] = atomicAdd(&cntC[c[i]], 1);
#pragma unroll
  for (int i = 0; i < 4; ++i) if (ok[i]) rv[i] = atomicAdd(&cntV[v[i]], 1);
#pragma unroll
  for (int i = 0; i < 4; ++i) if (ok[i]) rankC[e[i]] = rc[i];
#pragma unroll
  for (int i = 0; i < 4; ++i) if (ok[i]) rankV[e[i]] = rv[i];
}

// ============ fused scans: each launch handles both C and N arrays ============
__device__ __forceinline__ void scan1_body(const int* __restrict__ cnt,
                                           int* __restrict__ off,
                                           int* __restrict__ bsum, int M, int bid,
                                           int* s) {
  int base = bid * 1024 + threadIdx.x * 4;
  int v[4];
  int tot = 0;
#pragma unroll
  for (int i = 0; i < 4; ++i) {
    int idx = base + i;
    v[i] = (idx < M) ? cnt[idx] : 0;
    tot += v[i];
  }
  s[threadIdx.x] = tot;
  __syncthreads();
  for (int d = 1; d < 256; d <<= 1) {
    int t = (threadIdx.x >= d) ? s[threadIdx.x - d] : 0;
    __syncthreads();
    s[threadIdx.x] += t;
    __syncthreads();
  }
  int excl = s[threadIdx.x] - tot;
#pragma unroll
  for (int i = 0; i < 4; ++i) {
    int idx = base + i;
    if (idx < M) off[idx] = excl;
    excl += v[i];
  }
  if (threadIdx.x == 255) bsum[bid] = s[255];
}

__global__ __launch_bounds__(256) void scanA(const int* __restrict__ cntC,
                                             int* __restrict__ offC,
                                             int* __restrict__ bsC, int Mc,
                                             const int* __restrict__ cntV,
                                             int* __restrict__ offV,
                                             int* __restrict__ bsV, int Mv, int nbC) {
  __shared__ int s[256];
  if ((int)blockIdx.x < nbC)
    scan1_body(cntC, offC, bsC, Mc, blockIdx.x, s);
  else
    scan1_body(cntV, offV, bsV, Mv, blockIdx.x - nbC, s);
}

__global__ __launch_bounds__(256) void scanB(int* __restrict__ bsC, int nbC,
                                             int* __restrict__ bsV, int nbV) {
  __shared__ int s[256];
  __shared__ int carry;
  int* bsum = (blockIdx.x == 0) ? bsC : bsV;
  int nb = (blockIdx.x == 0) ? nbC : nbV;
  if (threadIdx.x == 0) carry = 0;
  __syncthreads();
  for (int base = 0; base < nb; base += 256) {
    int idx = base + threadIdx.x;
    int v = (idx < nb) ? bsum[idx] : 0;
    s[threadIdx.x] = v;
    __syncthreads();
    for (int d = 1; d < 256; d <<= 1) {
      int t = (threadIdx.x >= d) ? s[threadIdx.x - d] : 0;
      __syncthreads();
      s[threadIdx.x] += t;
      __syncthreads();
    }
    if (idx < nb) bsum[idx] = s[threadIdx.x] - v + carry;
    __syncthreads();
    if (threadIdx.x == 0) carry += s[255];
    __syncthreads();
  }
}

__global__ __launch_bounds__(256) void scanC(int* __restrict__ offC,
                                             const int* __restrict__ bsC, int Mc,
                                             int* __restrict__ offV,
                                             const int* __restrict__ bsV, int Mv,
                                             int E, int gC) {
  if ((int)blockIdx.x < gC) {
    int idx = blockIdx.x * 256 + threadIdx.x;
    if (idx < Mc) offC[idx] += bsC[idx >> 10];
    if (idx == Mc) offC[Mc] = E;
  } else {
    int idx = (blockIdx.x - gC) * 256 + threadIdx.x;
    if (idx < Mv) offV[idx] += bsV[idx >> 10];
    if (idx == Mv) offV[Mv] = E;
  }
}

// ====== fused scatter + LDS-free lin GEMM v2c, interleaved roles ======
// Every 3rd block (bid%3==0, bid<3*sgrid) is a scatter block.
// lin: 4 waves x 16 rows; B-fragments read DIRECTLY from global W (L2-resident);
// no LDS, no barriers.
__global__ __launch_bounds__(256) void lin_scatter(
    const float* __restrict__ X, const unsigned short* __restrict__ Wbf,
    const float* __restrict__ bias, unsigned short* __restrict__ out,
    unsigned short* __restrict__ bfdst, int M,
    const int* __restrict__ ci, const int* __restrict__ vi,
    const float* __restrict__ ew, const int* __restrict__ offC,
    const int* __restrict__ offV, const int* __restrict__ rankC,
    const int* __restrict__ rankV, int2* __restrict__ edataC,
    int2* __restrict__ edataV, int E, int sgrid) {
  const int tid = threadIdx.x;
  const int bid = blockIdx.x;
  const int s3 = 3 * sgrid;

  bool isScatter;
  int sidx = 0, lidx;
  if (bid < s3) {
    if (bid % 3 == 0) {
      isScatter = true;
      sidx = bid / 3;
    } else {
      isScatter = false;
      lidx = bid - bid / 3 - 1;
    }
  } else {
    isScatter = false;
    lidx = bid - sgrid;
  }

  if (isScatter) {
    int gtid = sidx * 256 + tid;
    int T = sgrid * 256;
    int e[2], c[2], v[2], wb[2], rc[2], rv[2];
    bool ok[2];
#pragma unroll
    for (int i = 0; i < 2; ++i) {
      e[i] = gtid + i * T;
      ok[i] = e[i] < E;
    }
#pragma unroll
    for (int i = 0; i < 2; ++i) if (ok[i]) c[i] = ci[e[i]];
#pragma unroll
    for (int i = 0; i < 2; ++i) if (ok[i]) v[i] = vi[e[i]];
#pragma unroll
    for (int i = 0; i < 2; ++i) if (ok[i]) wb[i] = __float_as_int(ew[e[i]]);
#pragma unroll
    for (int i = 0; i < 2; ++i) if (ok[i]) rc[i] = rankC[e[i]];
#pragma unroll
    for (int i = 0; i < 2; ++i) if (ok[i]) rv[i] = rankV[e[i]];
#pragma unroll
    for (int i = 0; i < 2; ++i) if (ok[i]) edataC[offC[c[i]] + rc[i]] = make_int2(v[i], wb[i]);
#pragma unroll
    for (int i = 0; i < 2; ++i) if (ok[i]) edataV[offV[v[i]] + rv[i]] = make_int2(c[i], wb[i]);
    return;
  }

  const int lane = tid & 63, wv = tid >> 6;
  const int lr = lane & 15, lg = lane >> 4;
  const int row0 = lidx * 64 + wv * 16;
  const int arow = row0 + lr;
  const bool rowok = arow < M;
  const float* xrow = X + (size_t)arow * 128;

  float4 x0[4], x1[4];
#pragma unroll
  for (int ks = 0; ks < 4; ++ks) {
    int kb = ks * 32 + lg * 8;
    if (rowok) {
      x0[ks] = *reinterpret_cast<const float4*>(xrow + kb);
      x1[ks] = *reinterpret_cast<const float4*>(xrow + kb + 4);
    } else {
      x0[ks] = make_float4(0.f, 0.f, 0.f, 0.f);
      x1[ks] = x0[ks];
    }
  }
  bf16x8 a[4];
#pragma unroll
  for (int ks = 0; ks < 4; ++ks) {
    a[ks] = (bf16x8){(short)f2bf(x0[ks].x), (short)f2bf(x0[ks].y),
                     (short)f2bf(x0[ks].z), (short)f2bf(x0[ks].w),
                     (short)f2bf(x1[ks].x), (short)f2bf(x1[ks].y),
                     (short)f2bf(x1[ks].z), (short)f2bf(x1[ks].w)};
    if (rowok)
      *reinterpret_cast<bf16x8*>(&bfdst[(size_t)arow * 256 + 128 + ks * 32 + lg * 8]) = a[ks];
  }

  f32x4 acc[8];
#pragma unroll
  for (int nf = 0; nf < 8; ++nf) acc[nf] = (f32x4)(0.f);
#pragma unroll
  for (int ks = 0; ks < 4; ++ks) {
#pragma unroll
    for (int nf = 0; nf < 8; ++nf) {
      bf16x8 b = *reinterpret_cast<const bf16x8*>(
          &Wbf[(size_t)(nf * 16 + lr) * 128 + ks * 32 + lg * 8]);
      acc[nf] = __builtin_amdgcn_mfma_f32_16x16x32_bf16(a[ks], b, acc[nf], 0, 0, 0);
    }
  }

#pragma unroll
  for (int nf = 0; nf < 8; ++nf) {
    int col = nf * 16 + lr;
    float bv = bias[col];
#pragma unroll
    for (int reg = 0; reg < 4; ++reg) {
      int grow = row0 + lg * 4 + reg;
      if (grow < M) out[(size_t)grow * 256 + col] = f2bf(acc[nf][reg] + bv);
    }
  }
}

// ---------------- segmented gather*gate reduce -> mean (bf16 src/out) ----------------
__global__ __launch_bounds__(256) void seg_reduce(const int* __restrict__ off,
                                                  const int2* __restrict__ edata,
                                                  const float* __restrict__ gw,
                                                  const float* __restrict__ gb,
                                                  const unsigned short* __restrict__ src,
                                                  int srcStride,
                                                  unsigned short* __restrict__ out,
                                                  int outStride, int M) {
  int seg = blockIdx.x * 4 + (threadIdx.x >> 6);
  if (seg >= M) return;
  int j = threadIdx.x & 63;
  int start = off[seg], end = off[seg + 1];
  float gwa = gw[2 * j], gwb = gw[2 * j + 1];
  float gba = gb[2 * j], gbb = gb[2 * j + 1];
  float a0 = 0.f, a1 = 0.f;
  int p = start;
  for (; p + 4 <= end; p += 4) {
    int2 e0 = edata[p], e1 = edata[p + 1], e2 = edata[p + 2], e3 = edata[p + 3];
    unsigned int v0 = *reinterpret_cast<const unsigned int*>(&src[(size_t)e0.x * srcStride + 2 * j]);
    unsigned int v1 = *reinterpret_cast<const unsigned int*>(&src[(size_t)e1.x * srcStride + 2 * j]);
    unsigned int v2 = *reinterpret_cast<const unsigned int*>(&src[(size_t)e2.x * srcStride + 2 * j]);
    unsigned int v3 = *reinterpret_cast<const unsigned int*>(&src[(size_t)e3.x * srcStride + 2 * j]);
    float w0 = __int_as_float(e0.y), w1 = __int_as_float(e1.y);
    float w2 = __int_as_float(e2.y), w3 = __int_as_float(e3.y);
    a0 += bf2f((unsigned short)(v0 & 0xffff)) * sigm(w0 * gwa + gba)
        + bf2f((unsigned short)(v1 & 0xffff)) * sigm(w1 * gwa + gba)
        + bf2f((unsigned short)(v2 & 0xffff)) * sigm(w2 * gwa + gba)
        + bf2f((unsigned short)(v3 & 0xffff)) * sigm(w3 * gwa + gba);
    a1 += bf2f((unsigned short)(v0 >> 16)) * sigm(w0 * gwb + gbb)
        + bf2f((unsigned short)(v1 >> 16)) * sigm(w1 * gwb + gbb)
        + bf2f((unsigned short)(v2 >> 16)) * sigm(w2 * gwb + gbb)
        + bf2f((unsigned short)(v3 >> 16)) * sigm(w3 * gwb + gbb);
  }
  if (p + 2 <= end) {
    int2 e0 = edata[p], e1 = edata[p + 1];
    unsigned int v0 = *reinterpret_cast<const unsigned int*>(&src[(size_t)e0.x * srcStride + 2 * j]);
    unsigned int v1 = *reinterpret_cast<const unsigned int*>(&src[(size_t)e1.x * srcStride + 2 * j]);
    float w0 = __int_as_float(e0.y), w1 = __int_as_float(e1.y);
    a0 += bf2f((unsigned short)(v0 & 0xffff)) * sigm(w0 * gwa + gba)
        + bf2f((unsigned short)(v1 & 0xffff)) * sigm(w1 * gwa + gba);
    a1 += bf2f((unsigned short)(v0 >> 16)) * sigm(w0 * gwb + gbb)
        + bf2f((unsigned short)(v1 >> 16)) * sigm(w1 * gwb + gbb);
    p += 2;
  }
  if (p < end) {
    int2 e0 = edata[p];
    unsigned int v0 = *reinterpret_cast<const unsigned int*>(&src[(size_t)e0.x * srcStride + 2 * j]);
    float w0 = __int_as_float(e0.y);
    a0 += bf2f((unsigned short)(v0 & 0xffff)) * sigm(w0 * gwa + gba);
    a1 += bf2f((unsigned short)(v0 >> 16)) * sigm(w0 * gwb + gbb);
  }
  int cnt = end - start;
  float inv = 1.f / (float)(cnt > 1 ? cnt : 1);
  unsigned int packed = (unsigned int)f2bf(a0 * inv) | ((unsigned int)f2bf(a1 * inv) << 16);
  *reinterpret_cast<unsigned int*>(&out[(size_t)seg * outStride + 2 * j]) = packed;
}

// ------- LDS-free lin GEMM (c2v): 4 waves x 16 rows; W from global/L2 -------
__global__ __launch_bounds__(256) void gemm_lin_reg(const float* __restrict__ X,
                                                    const unsigned short* __restrict__ Wbf,
                                                    const float* __restrict__ bias,
                                                    unsigned short* __restrict__ out,
                                                    int M) {
  const int tid = threadIdx.x;
  const int lane = tid & 63, wv = tid >> 6;
  const int lr = lane & 15, lg = lane >> 4;
  const int row0 = blockIdx.x * 64 + wv * 16;
  const int arow = row0 + lr;
  const bool rowok = arow < M;
  const float* xrow = X + (size_t)arow * 128;

  float4 x0[4], x1[4];
#pragma unroll
  for (int ks = 0; ks < 4; ++ks) {
    int kb = ks * 32 + lg * 8;
    if (rowok) {
      x0[ks] = *reinterpret_cast<const float4*>(xrow + kb);
      x1[ks] = *reinterpret_cast<const float4*>(xrow + kb + 4);
    } else {
      x0[ks] = make_float4(0.f, 0.f, 0.f, 0.f);
      x1[ks] = x0[ks];
    }
  }
  bf16x8 a[4];
#pragma unroll
  for (int ks = 0; ks < 4; ++ks)
    a[ks] = (bf16x8){(short)f2bf(x0[ks].x), (short)f2bf(x0[ks].y),
                     (short)f2bf(x0[ks].z), (short)f2bf(x0[ks].w),
                     (short)f2bf(x1[ks].x), (short)f2bf(x1[ks].y),
                     (short)f2bf(x1[ks].z), (short)f2bf(x1[ks].w)};

  f32x4 acc[8];
#pragma unroll
  for (int nf = 0; nf < 8; ++nf) acc[nf] = (f32x4)(0.f);
#pragma unroll
  for (int ks = 0; ks < 4; ++ks) {
#pragma unroll
    for (int nf = 0; nf < 8; ++nf) {
      bf16x8 b = *reinterpret_cast<const bf16x8*>(
          &Wbf[(size_t)(nf * 16 + lr) * 128 + ks * 32 + lg * 8]);
      acc[nf] = __builtin_amdgcn_mfma_f32_16x16x32_bf16(a[ks], b, acc[nf], 0, 0, 0);
    }
  }
#pragma unroll
  for (int nf = 0; nf < 8; ++nf) {
    int col = nf * 16 + lr;
    float bv = bias[col];
#pragma unroll
    for (int reg = 0; reg < 4; ++reg) {
      int grow = row0 + lg * 4 + reg;
      if (grow < M) out[(size_t)grow * 128 + col] = f2bf(acc[nf][reg] + bv);
    }
  }
}

// ------- LDS-free update GEMM (K=256): 4 waves x 16 rows; wave-local LN; ReLU -------
template <bool CAT>
__global__ __launch_bounds__(256) void gemm_upd_reg(const unsigned short* __restrict__ Xa,
                                                    const float* __restrict__ base,
                                                    const unsigned short* __restrict__ Wbf,
                                                    const float* __restrict__ bias,
                                                    const float* __restrict__ lng,
                                                    const float* __restrict__ lnb,
                                                    float* __restrict__ out, int M) {
  const int tid = threadIdx.x;
  const int lane = tid & 63, wv = tid >> 6;
  const int lr = lane & 15, lg = lane >> 4;
  const int row0 = blockIdx.x * 64 + wv * 16;
  const int arow = row0 + lr;
  const bool rowok = arow < M;

  bf16x8 a[8];
  if constexpr (CAT) {
    const unsigned short* xr = Xa + (size_t)arow * 256;
#pragma unroll
    for (int ks = 0; ks < 8; ++ks)
      a[ks] = rowok ? *reinterpret_cast<const bf16x8*>(xr + ks * 32 + lg * 8) : (bf16x8)(short)0;
  } else {
    const unsigned short* ar = Xa + (size_t)arow * 128;
#pragma unroll
    for (int ks = 0; ks < 4; ++ks)
      a[ks] = rowok ? *reinterpret_cast<const bf16x8*>(ar + ks * 32 + lg * 8) : (bf16x8)(short)0;
    const float* br = base + (size_t)arow * 128;
#pragma unroll
    for (int ks = 4; ks < 8; ++ks) {
      float4 f0 = make_float4(0.f, 0.f, 0.f, 0.f), f1 = f0;
      if (rowok) {
        int kb = (ks - 4) * 32 + lg * 8;
        f0 = *reinterpret_cast<const float4*>(br + kb);
        f1 = *reinterpret_cast<const float4*>(br + kb + 4);
      }
      a[ks] = (bf16x8){(short)f2bf(f0.x), (short)f2bf(f0.y), (short)f2bf(f0.z), (short)f2bf(f0.w),
                       (short)f2bf(f1.x), (short)f2bf(f1.y), (short)f2bf(f1.z), (short)f2bf(f1.w)};
    }
  }

  f32x4 acc[8];
#pragma unroll
  for (int nf = 0; nf < 8; ++nf) acc[nf] = (f32x4)(0.f);
#pragma unroll
  for (int ks = 0; ks < 8; ++ks) {
#pragma unroll
    for (int nf = 0; nf < 8; ++nf) {
      bf16x8 b = *reinterpret_cast<const bf16x8*>(
          &Wbf[(size_t)(nf * 16 + lr) * 256 + ks * 32 + lg * 8]);
      acc[nf] = __builtin_amdgcn_mfma_f32_16x16x32_bf16(a[ks], b, acc[nf], 0, 0, 0);
    }
  }

  float bv[8], gv[8], lv[8];
#pragma unroll
  for (int nf = 0; nf < 8; ++nf) {
    int col = nf * 16 + lr;
    bv[nf] = bias[col];
    gv[nf] = lng[col];
    lv[nf] = lnb[col];
  }
#pragma unroll
  for (int reg = 0; reg < 4; ++reg) {
    float z[8];
    float s = 0.f, q = 0.f;
#pragma unroll
    for (int nf = 0; nf < 8; ++nf) {
      z[nf] = acc[nf][reg] + bv[nf];
      s += z[nf];
      q += z[nf] * z[nf];
    }
#pragma unroll
    for (int m = 1; m < 16; m <<= 1) {
      s += __shfl_xor(s, m);
      q += __shfl_xor(q, m);
    }
    float mean = s * (1.f / 128.f);
    float var = q * (1.f / 128.f) - mean * mean;
    float rstd = rsqrtf(var + LN_EPS);
    int grow = row0 + lg * 4 + reg;
    if (grow < M) {
#pragma unroll
      for (int nf = 0; nf < 8; ++nf) {
        float y = (z[nf] - mean) * rstd * gv[nf] + lv[nf];
        out[(size_t)grow * 128 + nf * 16 + lr] = fmaxf(y, 0.f);
      }
    }
  }
}

extern "C" void kernel_launch(void* const* d_in, const int* in_sizes, int n_in,
                              void* d_out, int out_size, void* d_ws, size_t ws_size,
                              hipStream_t stream) {
  const float* vh = (const float*)d_in[0];
  const float* ch = (const float*)d_in[1];
  const int* ei = (const int*)d_in[2];   // [ci(E), vi(E)]
  const float* ew = (const float*)d_in[3];
  const float* v2c_lin_w = (const float*)d_in[4];
  const float* v2c_lin_b = (const float*)d_in[5];
  const float* v2c_gate_w = (const float*)d_in[6];
  const float* v2c_gate_b = (const float*)d_in[7];
  const float* v2c_upd_w = (const float*)d_in[8];
  const float* v2c_upd_b = (const float*)d_in[9];
  const float* v2c_ln_g = (const float*)d_in[10];
  const float* v2c_ln_b = (const float*)d_in[11];
  const float* c2v_lin_w = (const float*)d_in[12];
  const float* c2v_lin_b = (const float*)d_in[13];
  const float* c2v_gate_w = (const float*)d_in[14];
  const float* c2v_gate_b = (const float*)d_in[15];
  const float* c2v_upd_w = (const float*)d_in[16];
  const float* c2v_upd_b = (const float*)d_in[17];
  const float* c2v_ln_g = (const float*)d_in[18];
  const float* c2v_ln_b = (const float*)d_in[19];

  const int N = in_sizes[0] / 128;
  const int C = in_sizes[1] / 128;
  const int E = in_sizes[3];
  const int* ci = ei;
  const int* vi = ei + E;

  // ---- workspace layout (u16 units) ----
  unsigned short* Xcat = (unsigned short*)d_ws;         // N*256
  unsigned short* aggC = Xcat + (size_t)N * 256;        // C*128
  unsigned short* wbf = aggC + (size_t)C * 128;         // 98304
  unsigned short* wbfLinV = wbf;
  unsigned short* wbfUpdV = wbf + 16384;
  unsigned short* wbfLinC = wbf + 49152;
  unsigned short* wbfUpdC = wbf + 65536;
  int* offC = (int*)(wbf + 98304);                      // C+1
  int* offV = offC + (C + 1);                           // N+1
  size_t ofs = (size_t)((offV + (N + 1)) - (int*)d_ws);
  ofs = (ofs + 1) & ~(size_t)1;
  int2* edataC = (int2*)((int*)d_ws + ofs);             // E
  int2* edataV = edataC + E;                            // E
  int* cntC = (int*)aggC;
  int* cntV = cntC + C;
  int* bsumC = cntV + N;
  int* bsumV = bsumC + 512;
  int* rankC = bsumV + 512;
  int* rankV = rankC + E;

  float* vhNew = (float*)d_out;
  float* chNew = (float*)d_out + (size_t)N * 128;

  const int hgrid = (E + 4 * 256 - 1) / (4 * 256);
  const int sgrid = (E + 2 * 256 - 1) / (2 * 256);
  const int nbC = (C + 1023) / 1024;
  const int nbN = (N + 1023) / 1024;
  const int gC = (C + 1 + 255) / 256;
  const int gN = (N + 1 + 255) / 256;

  // ---- phase 1: weight cvt || hist+rank ----
  hipMemsetAsync(cntC, 0, (size_t)(C + N) * sizeof(int), stream);
  cvt_hist<<<384 + hgrid, 256, 0, stream>>>(v2c_lin_w, v2c_upd_w, c2v_lin_w, c2v_upd_w,
                                            wbfLinV, wbfUpdV, wbfLinC, wbfUpdC,
                                            ci, vi, cntC, cntV, rankC, rankV, E, hgrid);

  // ---- phase 2: fused scans ----
  scanA<<<nbC + nbN, 256, 0, stream>>>(cntC, offC, bsumC, C, cntV, offV, bsumV, N, nbC);
  scanB<<<2, 256, 0, stream>>>(bsumC, nbC, bsumV, nbN);
  scanC<<<gC + gN, 256, 0, stream>>>(offC, bsumC, C, offV, bsumV, N, E, gC);

  // ---- phase 3: scatter interleaved with LDS-free lin v2c ----
  lin_scatter<<<sgrid + (N + 63) / 64, 256, 0, stream>>>(
      vh, wbfLinV, v2c_lin_b, Xcat, Xcat, N,
      ci, vi, ew, offC, offV, rankC, rankV, edataC, edataV, E, sgrid);

  // ---- v2c ----
  seg_reduce<<<(C + 3) / 4, 256, 0, stream>>>(offC, edataC, v2c_gate_w, v2c_gate_b,
                                              Xcat, 256, aggC, 128, C);
  gemm_upd_reg<false><<<(C + 63) / 64, 256, 0, stream>>>(aggC, ch, wbfUpdV, v2c_upd_b,
                                                         v2c_ln_g, v2c_ln_b, chNew, C);

  // ---- c2v ----
  unsigned short* tmpC = aggC;   // reuse (agg_c dead after upd)
  gemm_lin_reg<<<(C + 63) / 64, 256, 0, stream>>>(chNew, wbfLinC, c2v_lin_b, tmpC, C);
  // agg_v written over tmp_v in Xcat[:,0:128] (tmp_v dead after v2c seg_reduce)
  seg_reduce<<<(N + 3) / 4, 256, 0, stream>>>(offV, edataV, c2v_gate_w, c2v_gate_b,
                                              tmpC, 128, Xcat, 256, N);
  gemm_upd_reg<true><<<(N + 63) / 64, 256, 0, stream>>>(Xcat, nullptr, wbfUpdC,
                                                        c2v_upd_b, c2v_ln_g, c2v_ln_b,
                                                        vhNew, N);
}

// Round 14
// 315.238 us; speedup vs baseline: 1.4662x; 1.4662x over previous
//
#include <hip/hip_runtime.h>

#define LN_EPS 1e-5f

typedef float f32x4 __attribute__((ext_vector_type(4)));
typedef short bf16x8 __attribute__((ext_vector_type(8)));
typedef unsigned short u16x4 __attribute__((ext_vector_type(4)));

__device__ __forceinline__ unsigned short f2bf(float f) {
  unsigned int u = __float_as_uint(f);
  u = (u + 0x7fffu + ((u >> 16) & 1u)) >> 16;
  return (unsigned short)u;
}
__device__ __forceinline__ float bf2f(unsigned short h) {
  return __uint_as_float((unsigned int)h << 16);
}
__device__ __forceinline__ float sigm(float x) {
  return 1.f / (1.f + __expf(-x));
}

// ============ fused: weight cvt (blocks [0,384)) + hist+rank (rest) ============
__global__ __launch_bounds__(256) void cvt_hist(const float* __restrict__ wa,
                                                const float* __restrict__ wb,
                                                const float* __restrict__ wc,
                                                const float* __restrict__ wd,
                                                unsigned short* __restrict__ oa,
                                                unsigned short* __restrict__ ob,
                                                unsigned short* __restrict__ oc,
                                                unsigned short* __restrict__ od,
                                                const int* __restrict__ ci,
                                                const int* __restrict__ vi,
                                                int* __restrict__ cntC,
                                                int* __restrict__ cntV,
                                                int* __restrict__ rankC,
                                                int* __restrict__ rankV, int E, int hgrid) {
  if ((int)blockIdx.x < 384) {
    int i = blockIdx.x * 256 + threadIdx.x;
    if (i < 16384) oa[i] = f2bf(wa[i]);
    else if (i < 49152) ob[i - 16384] = f2bf(wb[i - 16384]);
    else if (i < 65536) oc[i - 49152] = f2bf(wc[i - 49152]);
    else if (i < 98304) od[i - 65536] = f2bf(wd[i - 65536]);
    return;
  }
  int hb = blockIdx.x - 384;
  int tid = hb * 256 + threadIdx.x;
  int T = hgrid * 256;
  int e[4], c[4], v[4];
  bool ok[4];
#pragma unroll
  for (int i = 0; i < 4; ++i) {
    e[i] = tid + i * T;
    ok[i] = e[i] < E;
  }
#pragma unroll
  for (int i = 0; i < 4; ++i) if (ok[i]) c[i] = ci[e[i]];
#pragma unroll
  for (int i = 0; i < 4; ++i) if (ok[i]) v[i] = vi[e[i]];
  int rc[4], rv[4];
#pragma unroll
  for (int i = 0; i < 4; ++i) if (ok[i]) rc[i] = atomicAdd(&cntC[c[i]], 1);
#pragma unroll
  for (int i = 0; i < 4; ++i) if (ok[i]) rv[i] = atomicAdd(&cntV[v[i]], 1);
#pragma unroll
  for (int i = 0; i < 4; ++i) if (ok[i]) rankC[e[i]] = rc[i];
#pragma unroll
  for (int i = 0; i < 4; ++i) if (ok[i]) rankV[e[i]] = rv[i];
}

// ============ fused scans: each launch handles both C and N arrays ============
__device__ __forceinline__ void scan1_body(const int* __restrict__ cnt,
                                           int* __restrict__ off,
                                           int* __restrict__ bsum, int M, int bid,
                                           int* s) {
  int base = bid * 1024 + threadIdx.x * 4;
  int v[4];
  int tot = 0;
#pragma unroll
  for (int i = 0; i < 4; ++i) {
    int idx = base + i;
    v[i] = (idx < M) ? cnt[idx] : 0;
    tot += v[i];
  }
  s[threadIdx.x] = tot;
  __syncthreads();
  for (int d = 1; d < 256; d <<= 1) {
    int t = (threadIdx.x >= d) ? s[threadIdx.x - d] : 0;
    __syncthreads();
    s[threadIdx.x] += t;
    __syncthreads();
  }
  int excl = s[threadIdx.x] - tot;
#pragma unroll
  for (int i = 0; i < 4; ++i) {
    int idx = base + i;
    if (idx < M) off[idx] = excl;
    excl += v[i];
  }
  if (threadIdx.x == 255) bsum[bid] = s[255];
}

__global__ __launch_bounds__(256) void scanA(const int* __restrict__ cntC,
                                             int* __restrict__ offC,
                                             int* __restrict__ bsC, int Mc,
                                             const int* __restrict__ cntV,
                                             int* __restrict__ offV,
                                             int* __restrict__ bsV, int Mv, int nbC) {
  __shared__ int s[256];
  if ((int)blockIdx.x < nbC)
    scan1_body(cntC, offC, bsC, Mc, blockIdx.x, s);
  else
    scan1_body(cntV, offV, bsV, Mv, blockIdx.x - nbC, s);
}

__global__ __launch_bounds__(256) void scanB(int* __restrict__ bsC, int nbC,
                                             int* __restrict__ bsV, int nbV) {
  __shared__ int s[256];
  __shared__ int carry;
  int* bsum = (blockIdx.x == 0) ? bsC : bsV;
  int nb = (blockIdx.x == 0) ? nbC : nbV;
  if (threadIdx.x == 0) carry = 0;
  __syncthreads();
  for (int base = 0; base < nb; base += 256) {
    int idx = base + threadIdx.x;
    int v = (idx < nb) ? bsum[idx] : 0;
    s[threadIdx.x] = v;
    __syncthreads();
    for (int d = 1; d < 256; d <<= 1) {
      int t = (threadIdx.x >= d) ? s[threadIdx.x - d] : 0;
      __syncthreads();
      s[threadIdx.x] += t;
      __syncthreads();
    }
    if (idx < nb) bsum[idx] = s[threadIdx.x] - v + carry;
    __syncthreads();
    if (threadIdx.x == 0) carry += s[255];
    __syncthreads();
  }
}

__global__ __launch_bounds__(256) void scanC(int* __restrict__ offC,
                                             const int* __restrict__ bsC, int Mc,
                                             int* __restrict__ offV,
                                             const int* __restrict__ bsV, int Mv,
                                             int E, int gC) {
  if ((int)blockIdx.x < gC) {
    int idx = blockIdx.x * 256 + threadIdx.x;
    if (idx < Mc) offC[idx] += bsC[idx >> 10];
    if (idx == Mc) offC[Mc] = E;
  } else {
    int idx = (blockIdx.x - gC) * 256 + threadIdx.x;
    if (idx < Mv) offV[idx] += bsV[idx >> 10];
    if (idx == Mv) offV[Mv] = E;
  }
}

// ====== fused scatter + lin GEMM v2c, interleaved roles (round-12 structure) ======
__global__ __launch_bounds__(512) void lin_scatter(
    const float* __restrict__ X, const unsigned short* __restrict__ Wbf,
    const float* __restrict__ bias, unsigned short* __restrict__ out,
    unsigned short* __restrict__ bfdst, int M,
    const int* __restrict__ ci, const int* __restrict__ vi,
    const float* __restrict__ ew, const int* __restrict__ offC,
    const int* __restrict__ offV, const int* __restrict__ rankC,
    const int* __restrict__ rankV, int2* __restrict__ edataC,
    int2* __restrict__ edataV, int E, int sgrid) {
  __shared__ unsigned short Bs[128][136];
  const int tid = threadIdx.x;
  const int bid = blockIdx.x;
  const int s3 = 3 * sgrid;

  bool isScatter;
  int sidx = 0, lidx;
  if (bid < s3) {
    if (bid % 3 == 0) {
      isScatter = true;
      sidx = bid / 3;
    } else {
      isScatter = false;
      lidx = bid - bid / 3 - 1;
    }
  } else {
    isScatter = false;
    lidx = bid - sgrid;
  }

  if (isScatter) {
    int gtid = sidx * 512 + tid;
    int T = sgrid * 512;
    int e[2], c[2], v[2], wb[2], rc[2], rv[2];
    bool ok[2];
#pragma unroll
    for (int i = 0; i < 2; ++i) {
      e[i] = gtid + i * T;
      ok[i] = e[i] < E;
    }
#pragma unroll
    for (int i = 0; i < 2; ++i) if (ok[i]) c[i] = ci[e[i]];
#pragma unroll
    for (int i = 0; i < 2; ++i) if (ok[i]) v[i] = vi[e[i]];
#pragma unroll
    for (int i = 0; i < 2; ++i) if (ok[i]) wb[i] = __float_as_int(ew[e[i]]);
#pragma unroll
    for (int i = 0; i < 2; ++i) if (ok[i]) rc[i] = rankC[e[i]];
#pragma unroll
    for (int i = 0; i < 2; ++i) if (ok[i]) rv[i] = rankV[e[i]];
#pragma unroll
    for (int i = 0; i < 2; ++i) if (ok[i]) edataC[offC[c[i]] + rc[i]] = make_int2(v[i], wb[i]);
#pragma unroll
    for (int i = 0; i < 2; ++i) if (ok[i]) edataV[offV[v[i]] + rv[i]] = make_int2(c[i], wb[i]);
    return;
  }

  const int lane = tid & 63, wv = tid >> 6;
  const int lr = lane & 15, lg = lane >> 4;
  const int row0 = lidx * 128 + wv * 16;
  const int arow = row0 + lr;
  const bool rowok = arow < M;
  const float* xrow = X + (size_t)arow * 128;

  float4 x0[4], x1[4];
#pragma unroll
  for (int ks = 0; ks < 4; ++ks) {
    int kb = ks * 32 + lg * 8;
    if (rowok) {
      x0[ks] = *reinterpret_cast<const float4*>(xrow + kb);
      x1[ks] = *reinterpret_cast<const float4*>(xrow + kb + 4);
    } else {
      x0[ks] = make_float4(0.f, 0.f, 0.f, 0.f);
      x1[ks] = x0[ks];
    }
  }

#pragma unroll
  for (int it = 0; it < 4; ++it) {
    int q = tid + it * 512;
    int n = q >> 4, kq = (q & 15) * 8;
    *reinterpret_cast<bf16x8*>(&Bs[n][kq]) =
        *reinterpret_cast<const bf16x8*>(&Wbf[(size_t)n * 128 + kq]);
  }

  bf16x8 a[4];
#pragma unroll
  for (int ks = 0; ks < 4; ++ks) {
    a[ks] = (bf16x8){(short)f2bf(x0[ks].x), (short)f2bf(x0[ks].y),
                     (short)f2bf(x0[ks].z), (short)f2bf(x0[ks].w),
                     (short)f2bf(x1[ks].x), (short)f2bf(x1[ks].y),
                     (short)f2bf(x1[ks].z), (short)f2bf(x1[ks].w)};
    if (rowok)
      *reinterpret_cast<bf16x8*>(&bfdst[(size_t)arow * 256 + 128 + ks * 32 + lg * 8]) = a[ks];
  }
  __syncthreads();

  f32x4 acc[8];
#pragma unroll
  for (int nf = 0; nf < 8; ++nf) acc[nf] = (f32x4)(0.f);
#pragma unroll
  for (int ks = 0; ks < 4; ++ks) {
#pragma unroll
    for (int nf = 0; nf < 8; ++nf) {
      bf16x8 b = *reinterpret_cast<const bf16x8*>(&Bs[nf * 16 + lr][ks * 32 + lg * 8]);
      acc[nf] = __builtin_amdgcn_mfma_f32_16x16x32_bf16(a[ks], b, acc[nf], 0, 0, 0);
    }
  }

#pragma unroll
  for (int nf = 0; nf < 8; ++nf) {
    int col = nf * 16 + lr;
    float bv = bias[col];
#pragma unroll
    for (int reg = 0; reg < 4; ++reg) {
      int grow = row0 + lg * 4 + reg;
      if (grow < M) out[(size_t)grow * 256 + col] = f2bf(acc[nf][reg] + bv);
    }
  }
}

// ---------------- segmented gather*gate reduce -> mean (bf16 src/out) ----------------
__global__ __launch_bounds__(256) void seg_reduce(const int* __restrict__ off,
                                                  const int2* __restrict__ edata,
                                                  const float* __restrict__ gw,
                                                  const float* __restrict__ gb,
                                                  const unsigned short* __restrict__ src,
                                                  int srcStride,
                                                  unsigned short* __restrict__ out,
                                                  int outStride, int M) {
  int seg = blockIdx.x * 4 + (threadIdx.x >> 6);
  if (seg >= M) return;
  int j = threadIdx.x & 63;
  int start = off[seg], end = off[seg + 1];
  float gwa = gw[2 * j], gwb = gw[2 * j + 1];
  float gba = gb[2 * j], gbb = gb[2 * j + 1];
  float a0 = 0.f, a1 = 0.f;
  int p = start;
  for (; p + 4 <= end; p += 4) {
    int2 e0 = edata[p], e1 = edata[p + 1], e2 = edata[p + 2], e3 = edata[p + 3];
    unsigned int v0 = *reinterpret_cast<const unsigned int*>(&src[(size_t)e0.x * srcStride + 2 * j]);
    unsigned int v1 = *reinterpret_cast<const unsigned int*>(&src[(size_t)e1.x * srcStride + 2 * j]);
    unsigned int v2 = *reinterpret_cast<const unsigned int*>(&src[(size_t)e2.x * srcStride + 2 * j]);
    unsigned int v3 = *reinterpret_cast<const unsigned int*>(&src[(size_t)e3.x * srcStride + 2 * j]);
    float w0 = __int_as_float(e0.y), w1 = __int_as_float(e1.y);
    float w2 = __int_as_float(e2.y), w3 = __int_as_float(e3.y);
    a0 += bf2f((unsigned short)(v0 & 0xffff)) * sigm(w0 * gwa + gba)
        + bf2f((unsigned short)(v1 & 0xffff)) * sigm(w1 * gwa + gba)
        + bf2f((unsigned short)(v2 & 0xffff)) * sigm(w2 * gwa + gba)
        + bf2f((unsigned short)(v3 & 0xffff)) * sigm(w3 * gwa + gba);
    a1 += bf2f((unsigned short)(v0 >> 16)) * sigm(w0 * gwb + gbb)
        + bf2f((unsigned short)(v1 >> 16)) * sigm(w1 * gwb + gbb)
        + bf2f((unsigned short)(v2 >> 16)) * sigm(w2 * gwb + gbb)
        + bf2f((unsigned short)(v3 >> 16)) * sigm(w3 * gwb + gbb);
  }
  if (p + 2 <= end) {
    int2 e0 = edata[p], e1 = edata[p + 1];
    unsigned int v0 = *reinterpret_cast<const unsigned int*>(&src[(size_t)e0.x * srcStride + 2 * j]);
    unsigned int v1 = *reinterpret_cast<const unsigned int*>(&src[(size_t)e1.x * srcStride + 2 * j]);
    float w0 = __int_as_float(e0.y), w1 = __int_as_float(e1.y);
    a0 += bf2f((unsigned short)(v0 & 0xffff)) * sigm(w0 * gwa + gba)
        + bf2f((unsigned short)(v1 & 0xffff)) * sigm(w1 * gwa + gba);
    a1 += bf2f((unsigned short)(v0 >> 16)) * sigm(w0 * gwb + gbb)
        + bf2f((unsigned short)(v1 >> 16)) * sigm(w1 * gwb + gbb);
    p += 2;
  }
  if (p < end) {
    int2 e0 = edata[p];
    unsigned int v0 = *reinterpret_cast<const unsigned int*>(&src[(size_t)e0.x * srcStride + 2 * j]);
    float w0 = __int_as_float(e0.y);
    a0 += bf2f((unsigned short)(v0 & 0xffff)) * sigm(w0 * gwa + gba);
    a1 += bf2f((unsigned short)(v0 >> 16)) * sigm(w0 * gwb + gbb);
  }
  int cnt = end - start;
  float inv = 1.f / (float)(cnt > 1 ? cnt : 1);
  unsigned int packed = (unsigned int)f2bf(a0 * inv) | ((unsigned int)f2bf(a1 * inv) << 16);
  *reinterpret_cast<unsigned int*>(&out[(size_t)seg * outStride + 2 * j]) = packed;
}

// ------- lin GEMM (c2v): per-tile, 8 waves x 16 rows -------
__global__ __launch_bounds__(512) void gemm_lin_reg(const float* __restrict__ X,
                                                    const unsigned short* __restrict__ Wbf,
                                                    const float* __restrict__ bias,
                                                    unsigned short* __restrict__ out,
                                                    int M) {
  __shared__ unsigned short Bs[128][136];
  const int tid = threadIdx.x;
  const int lane = tid & 63, wv = tid >> 6;
  const int lr = lane & 15, lg = lane >> 4;
  const int row0 = blockIdx.x * 128 + wv * 16;
  const int arow = row0 + lr;
  const bool rowok = arow < M;
  const float* xrow = X + (size_t)arow * 128;

  float4 x0[4], x1[4];
#pragma unroll
  for (int ks = 0; ks < 4; ++ks) {
    int kb = ks * 32 + lg * 8;
    if (rowok) {
      x0[ks] = *reinterpret_cast<const float4*>(xrow + kb);
      x1[ks] = *reinterpret_cast<const float4*>(xrow + kb + 4);
    } else {
      x0[ks] = make_float4(0.f, 0.f, 0.f, 0.f);
      x1[ks] = x0[ks];
    }
  }
#pragma unroll
  for (int it = 0; it < 4; ++it) {
    int q = tid + it * 512;
    int n = q >> 4, kq = (q & 15) * 8;
    *reinterpret_cast<bf16x8*>(&Bs[n][kq]) =
        *reinterpret_cast<const bf16x8*>(&Wbf[(size_t)n * 128 + kq]);
  }
  bf16x8 a[4];
#pragma unroll
  for (int ks = 0; ks < 4; ++ks)
    a[ks] = (bf16x8){(short)f2bf(x0[ks].x), (short)f2bf(x0[ks].y),
                     (short)f2bf(x0[ks].z), (short)f2bf(x0[ks].w),
                     (short)f2bf(x1[ks].x), (short)f2bf(x1[ks].y),
                     (short)f2bf(x1[ks].z), (short)f2bf(x1[ks].w)};
  __syncthreads();

  f32x4 acc[8];
#pragma unroll
  for (int nf = 0; nf < 8; ++nf) acc[nf] = (f32x4)(0.f);
#pragma unroll
  for (int ks = 0; ks < 4; ++ks) {
#pragma unroll
    for (int nf = 0; nf < 8; ++nf) {
      bf16x8 b = *reinterpret_cast<const bf16x8*>(&Bs[nf * 16 + lr][ks * 32 + lg * 8]);
      acc[nf] = __builtin_amdgcn_mfma_f32_16x16x32_bf16(a[ks], b, acc[nf], 0, 0, 0);
    }
  }
#pragma unroll
  for (int nf = 0; nf < 8; ++nf) {
    int col = nf * 16 + lr;
    float bv = bias[col];
#pragma unroll
    for (int reg = 0; reg < 4; ++reg) {
      int grow = row0 + lg * 4 + reg;
      if (grow < M) out[(size_t)grow * 128 + col] = f2bf(acc[nf][reg] + bv);
    }
  }
}

// ------- update GEMM (K=256): per-tile, async half-W staging (issue-early /
// write-late), wave-local LN, ReLU -------
template <bool CAT>
__global__ __launch_bounds__(512) void gemm_upd_reg(const unsigned short* __restrict__ Xa,
                                                    const float* __restrict__ base,
                                                    const unsigned short* __restrict__ Wbf,
                                                    const float* __restrict__ bias,
                                                    const float* __restrict__ lng,
                                                    const float* __restrict__ lnb,
                                                    float* __restrict__ out, int M) {
  __shared__ unsigned short Bs[128][136];
  const int tid = threadIdx.x;
  const int lane = tid & 63, wv = tid >> 6;
  const int lr = lane & 15, lg = lane >> 4;
  const int row0 = blockIdx.x * 128 + wv * 16;
  const int arow = row0 + lr;
  const bool rowok = arow < M;

  bf16x8 a[8];
  if constexpr (CAT) {
    const unsigned short* xr = Xa + (size_t)arow * 256;
#pragma unroll
    for (int ks = 0; ks < 8; ++ks)
      a[ks] = rowok ? *reinterpret_cast<const bf16x8*>(xr + ks * 32 + lg * 8) : (bf16x8)(short)0;
  } else {
    const unsigned short* ar = Xa + (size_t)arow * 128;
#pragma unroll
    for (int ks = 0; ks < 4; ++ks)
      a[ks] = rowok ? *reinterpret_cast<const bf16x8*>(ar + ks * 32 + lg * 8) : (bf16x8)(short)0;
    const float* br = base + (size_t)arow * 128;
#pragma unroll
    for (int ks = 4; ks < 8; ++ks) {
      float4 f0 = make_float4(0.f, 0.f, 0.f, 0.f), f1 = f0;
      if (rowok) {
        int kb = (ks - 4) * 32 + lg * 8;
        f0 = *reinterpret_cast<const float4*>(br + kb);
        f1 = *reinterpret_cast<const float4*>(br + kb + 4);
      }
      a[ks] = (bf16x8){(short)f2bf(f0.x), (short)f2bf(f0.y), (short)f2bf(f0.z), (short)f2bf(f0.w),
                       (short)f2bf(f1.x), (short)f2bf(f1.y), (short)f2bf(f1.z), (short)f2bf(f1.w)};
    }
  }

  // W staging split: loadW -> registers (issue early), writeW -> LDS (late)
  bf16x8 wr[4];
  auto loadW = [&](int kh) {
#pragma unroll
    for (int it = 0; it < 4; ++it) {
      int q = tid + it * 512;
      int n = q >> 4, kq = (q & 15) * 8;
      wr[it] = *reinterpret_cast<const bf16x8*>(&Wbf[(size_t)n * 256 + kh * 128 + kq]);
    }
  };
  auto writeW = [&]() {
#pragma unroll
    for (int it = 0; it < 4; ++it) {
      int q = tid + it * 512;
      int n = q >> 4, kq = (q & 15) * 8;
      *reinterpret_cast<bf16x8*>(&Bs[n][kq]) = wr[it];
    }
  };

  f32x4 acc[8];
#pragma unroll
  for (int nf = 0; nf < 8; ++nf) acc[nf] = (f32x4)(0.f);

  loadW(0);
  writeW();
  __syncthreads();
  loadW(1);               // issue half-1 loads early: latency hides under MFMAs
#pragma unroll
  for (int ks = 0; ks < 4; ++ks) {
#pragma unroll
    for (int nf = 0; nf < 8; ++nf) {
      bf16x8 b = *reinterpret_cast<const bf16x8*>(&Bs[nf * 16 + lr][ks * 32 + lg * 8]);
      acc[nf] = __builtin_amdgcn_mfma_f32_16x16x32_bf16(a[ks], b, acc[nf], 0, 0, 0);
    }
  }
  __syncthreads();
  writeW();               // loads already returned; just LDS write
  __syncthreads();
#pragma unroll
  for (int ks = 4; ks < 8; ++ks) {
#pragma unroll
    for (int nf = 0; nf < 8; ++nf) {
      bf16x8 b = *reinterpret_cast<const bf16x8*>(&Bs[nf * 16 + lr][(ks - 4) * 32 + lg * 8]);
      acc[nf] = __builtin_amdgcn_mfma_f32_16x16x32_bf16(a[ks], b, acc[nf], 0, 0, 0);
    }
  }

  float bv[8], gv[8], lv[8];
#pragma unroll
  for (int nf = 0; nf < 8; ++nf) {
    int col = nf * 16 + lr;
    bv[nf] = bias[col];
    gv[nf] = lng[col];
    lv[nf] = lnb[col];
  }
#pragma unroll
  for (int reg = 0; reg < 4; ++reg) {
    float z[8];
    float s = 0.f, q = 0.f;
#pragma unroll
    for (int nf = 0; nf < 8; ++nf) {
      z[nf] = acc[nf][reg] + bv[nf];
      s += z[nf];
      q += z[nf] * z[nf];
    }
#pragma unroll
    for (int m = 1; m < 16; m <<= 1) {
      s += __shfl_xor(s, m);
      q += __shfl_xor(q, m);
    }
    float mean = s * (1.f / 128.f);
    float var = q * (1.f / 128.f) - mean * mean;
    float rstd = rsqrtf(var + LN_EPS);
    int grow = row0 + lg * 4 + reg;
    if (grow < M) {
#pragma unroll
      for (int nf = 0; nf < 8; ++nf) {
        float y = (z[nf] - mean) * rstd * gv[nf] + lv[nf];
        out[(size_t)grow * 128 + nf * 16 + lr] = fmaxf(y, 0.f);
      }
    }
  }
}

extern "C" void kernel_launch(void* const* d_in, const int* in_sizes, int n_in,
                              void* d_out, int out_size, void* d_ws, size_t ws_size,
                              hipStream_t stream) {
  const float* vh = (const float*)d_in[0];
  const float* ch = (const float*)d_in[1];
  const int* ei = (const int*)d_in[2];   // [ci(E), vi(E)]
  const float* ew = (const float*)d_in[3];
  const float* v2c_lin_w = (const float*)d_in[4];
  const float* v2c_lin_b = (const float*)d_in[5];
  const float* v2c_gate_w = (const float*)d_in[6];
  const float* v2c_gate_b = (const float*)d_in[7];
  const float* v2c_upd_w = (const float*)d_in[8];
  const float* v2c_upd_b = (const float*)d_in[9];
  const float* v2c_ln_g = (const float*)d_in[10];
  const float* v2c_ln_b = (const float*)d_in[11];
  const float* c2v_lin_w = (const float*)d_in[12];
  const float* c2v_lin_b = (const float*)d_in[13];
  const float* c2v_gate_w = (const float*)d_in[14];
  const float* c2v_gate_b = (const float*)d_in[15];
  const float* c2v_upd_w = (const float*)d_in[16];
  const float* c2v_upd_b = (const float*)d_in[17];
  const float* c2v_ln_g = (const float*)d_in[18];
  const float* c2v_ln_b = (const float*)d_in[19];

  const int N = in_sizes[0] / 128;
  const int C = in_sizes[1] / 128;
  const int E = in_sizes[3];
  const int* ci = ei;
  const int* vi = ei + E;

  // ---- workspace layout (u16 units) ----
  unsigned short* Xcat = (unsigned short*)d_ws;         // N*256
  unsigned short* aggC = Xcat + (size_t)N * 256;        // C*128
  unsigned short* wbf = aggC + (size_t)C * 128;         // 98304
  unsigned short* wbfLinV = wbf;
  unsigned short* wbfUpdV = wbf + 16384;
  unsigned short* wbfLinC = wbf + 49152;
  unsigned short* wbfUpdC = wbf + 65536;
  int* offC = (int*)(wbf + 98304);                      // C+1
  int* offV = offC + (C + 1);                           // N+1
  size_t ofs = (size_t)((offV + (N + 1)) - (int*)d_ws);
  ofs = (ofs + 1) & ~(size_t)1;
  int2* edataC = (int2*)((int*)d_ws + ofs);             // E
  int2* edataV = edataC + E;                            // E
  int* cntC = (int*)aggC;
  int* cntV = cntC + C;
  int* bsumC = cntV + N;
  int* bsumV = bsumC + 512;
  int* rankC = bsumV + 512;
  int* rankV = rankC + E;

  float* vhNew = (float*)d_out;
  float* chNew = (float*)d_out + (size_t)N * 128;

  const int hgrid = (E + 4 * 256 - 1) / (4 * 256);
  const int sgrid = (E + 2 * 512 - 1) / (2 * 512);
  const int nbC = (C + 1023) / 1024;
  const int nbN = (N + 1023) / 1024;
  const int gC = (C + 1 + 255) / 256;
  const int gN = (N + 1 + 255) / 256;

  // ---- phase 1: weight cvt || hist+rank ----
  hipMemsetAsync(cntC, 0, (size_t)(C + N) * sizeof(int), stream);
  cvt_hist<<<384 + hgrid, 256, 0, stream>>>(v2c_lin_w, v2c_upd_w, c2v_lin_w, c2v_upd_w,
                                            wbfLinV, wbfUpdV, wbfLinC, wbfUpdC,
                                            ci, vi, cntC, cntV, rankC, rankV, E, hgrid);

  // ---- phase 2: fused scans ----
  scanA<<<nbC + nbN, 256, 0, stream>>>(cntC, offC, bsumC, C, cntV, offV, bsumV, N, nbC);
  scanB<<<2, 256, 0, stream>>>(bsumC, nbC, bsumV, nbN);
  scanC<<<gC + gN, 256, 0, stream>>>(offC, bsumC, C, offV, bsumV, N, E, gC);

  // ---- phase 3: scatter interleaved with lin v2c ----
  lin_scatter<<<sgrid + (N + 127) / 128, 512, 0, stream>>>(
      vh, wbfLinV, v2c_lin_b, Xcat, Xcat, N,
      ci, vi, ew, offC, offV, rankC, rankV, edataC, edataV, E, sgrid);

  // ---- v2c ----
  seg_reduce<<<(C + 3) / 4, 256, 0, stream>>>(offC, edataC, v2c_gate_w, v2c_gate_b,
                                              Xcat, 256, aggC, 128, C);
  gemm_upd_reg<false><<<(C + 127) / 128, 512, 0, stream>>>(aggC, ch, wbfUpdV, v2c_upd_b,
                                                           v2c_ln_g, v2c_ln_b, chNew, C);

  // ---- c2v ----
  unsigned short* tmpC = aggC;   // reuse (agg_c dead after upd)
  gemm_lin_reg<<<(C + 127) / 128, 512, 0, stream>>>(chNew, wbfLinC, c2v_lin_b, tmpC, C);
  // agg_v written over tmp_v in Xcat[:,0:128] (tmp_v dead after v2c seg_reduce)
  seg_reduce<<<(N + 3) / 4, 256, 0, stream>>>(offV, edataV, c2v_gate_w, c2v_gate_b,
                                              tmpC, 128, Xcat, 256, N);
  gemm_upd_reg<true><<<(N + 127) / 128, 512, 0, stream>>>(Xcat, nullptr, wbfUpdC,
                                                          c2v_upd_b, c2v_ln_g, c2v_ln_b,
                                                          vhNew, N);
}